// Round 2
// 345.945 us; speedup vs baseline: 1.2097x; 1.2097x over previous
//
#include <hip/hip_runtime.h>
#include <cstddef>

#define NB 32
#define NC 4
#define NH 512
#define NW 512
#define PLANE (NH * NW)
#define NSTEPS 8
#define SROWS 8                 // rows per strip (step kernel)
#define NSTRIP (NH / SROWS)     // 64 strips -> grid (64, 32) = 2048 blocks

typedef float v4f __attribute__((ext_vector_type(4)));

// Block-wide (256-thread) sum reduction. Valid result only in threadIdx.x==0.
__device__ __forceinline__ float blockReduce256(float v, float* sm) {
#pragma unroll
    for (int off = 32; off > 0; off >>= 1) v += __shfl_down(v, off, 64);
    int lane = threadIdx.x & 63;
    int wave = threadIdx.x >> 6;
    if (lane == 0) sm[wave] = v;
    __syncthreads();
    return (threadIdx.x == 0) ? ((sm[0] + sm[1]) + (sm[2] + sm[3])) : 0.0f;
}

// Per-(b,c) sums; ch1..3 copied to out with nontemporal ld/st (once-touched
// 200 MB must not evict the ch0 ping-pong set from L3). ch0 of t==0 batches is
// stored here too (their final result IS the input), so steps never copy.
// grid = NB*NC*16 = 2048, block = 256.
__global__ void mean_copy_kernel(const float* __restrict__ x,
                                 float* __restrict__ out,
                                 float* __restrict__ sumsAll,
                                 float* __restrict__ stepSums,
                                 const int* __restrict__ tg) {
    int id = blockIdx.x;
    int sub = id & 15;
    int plane = id >> 4;        // b*NC + c
    int c = plane & 3;
    int b = plane >> 4 >> 0;    // placeholder; recompute below for clarity
    b = plane >> 2;
    size_t base = (size_t)plane * PLANE + (size_t)sub * (PLANE / 16);
    const v4f* s4 = (const v4f*)(x + base);
    v4f* d4 = (v4f*)(out + base);
    const int nvec = PLANE / 16 / 4;    // 4096 float4 per chunk
    float s = 0.0f;
    if (c == 0) {
        bool doStore = (tg[b] == 0);    // t==0: out ch0 = x ch0, final
        for (int j = threadIdx.x; j < nvec; j += 256) {
            v4f v = s4[j];              // plain load: step 0 re-reads ch0
            s += (v.x + v.y) + (v.z + v.w);
            if (doStore) __builtin_nontemporal_store(v, &d4[j]);
        }
    } else {
        for (int j = threadIdx.x; j < nvec; j += 256) {
            v4f v = __builtin_nontemporal_load(&s4[j]);
            s += (v.x + v.y) + (v.z + v.w);
            __builtin_nontemporal_store(v, &d4[j]);
        }
    }
    __shared__ float sm[4];
    float tot = blockReduce256(s, sm);
    if (threadIdx.x == 0) {
        if (c == 0) atomicAdd(&stepSums[b], tot);       // step-0 ch0 sum
        else atomicAdd(&sumsAll[b * NC + c], tot);      // constant ch1..3 sums
    }
}

// One reaction-diffusion step, compacted to active batches (t[b] > stepIdx).
// grid = (NSTRIP, NB), block = 256. Each block: 8-row x 512-col strip,
// 4 rows/thread via a rolling 3-row register window; left/right halos come
// from __shfl (2 masked scalar loads per wave-row instead of 128).
// Final step for a batch (stepIdx == t[b]-1) writes directly to out ch0.
__global__ __launch_bounds__(256) void step_kernel(
    const float* __restrict__ x, float* __restrict__ out, float* __restrict__ ws,
    const float* __restrict__ sumsAll, const float* __restrict__ stepSums,
    const float* __restrict__ Wm, const float* __restrict__ bv,
    const int* __restrict__ tg, int stepIdx) {
    __shared__ int tSh[NB];
    __shared__ float prm[2];
    __shared__ float sm[4];
    if (threadIdx.x < NB) tSh[threadIdx.x] = tg[threadIdx.x];
    __syncthreads();

    // Compact: item -> batch with t > stepIdx (every thread computes the same).
    int item = blockIdx.y;
    int b = -1, tb = 0, cnt = 0;
#pragma unroll
    for (int bb = 0; bb < NB; ++bb) {
        int tv = tSh[bb];
        if (tv > stepIdx) {
            if (cnt == item) { b = bb; tb = tv; }
            ++cnt;
        }
    }
    if (b < 0) return;                  // idle block (uniform per block)

    if (threadIdx.x == 0) {
        const float inv = 1.0f / (float)PLANE;
        float f0 = stepSums[stepIdx * NB + b] * inv;
        float f1 = sumsAll[b * NC + 1] * inv;
        float f2 = sumsAll[b * NC + 2] * inv;
        float f3 = sumsAll[b * NC + 3] * inv;
        float z0 = f0 * Wm[0] + f1 * Wm[2] + f2 * Wm[4] + f3 * Wm[6] + bv[0];
        float z1 = f0 * Wm[1] + f1 * Wm[3] + f2 * Wm[5] + f3 * Wm[7] + bv[1];
        prm[0] = 0.2f / (1.0f + expf(-z0));     // D
        prm[1] = 0.1f / (1.0f + expf(-z1));     // rho
    }
    __syncthreads();
    float D = prm[0], rho = prm[1];

    const float* sp = (stepIdx == 0) ? (x + (size_t)b * NC * PLANE)
                    : (stepIdx & 1)  ? (ws + (size_t)b * PLANE)
                                     : (out + (size_t)b * NC * PLANE);
    bool finalStep = (stepIdx == tb - 1);
    float* dp = (finalStep || (stepIdx & 1)) ? (out + (size_t)b * NC * PLANE)
                                             : (ws + (size_t)b * PLANE);

    int col4 = threadIdx.x & 127;       // float4 index in row
    int x0 = col4 * 4;
    int half = threadIdx.x >> 7;        // 0 or 1
    int lane = threadIdx.x & 63;
    int y0 = blockIdx.x * SROWS + half * (SROWS / 2);   // 4 rows per thread

    v4f up = ((const v4f*)(sp + (size_t)((y0 - 1) & (NH - 1)) * NW))[col4];
    v4f cc = ((const v4f*)(sp + (size_t)y0 * NW))[col4];
    float acc = 0.0f;
#pragma unroll
    for (int k = 0; k < SROWS / 2; ++k) {
        int y = y0 + k;
        v4f dn = ((const v4f*)(sp + (size_t)((y + 1) & (NH - 1)) * NW))[col4];
        // Row halos: within a wave, col4 = lane + 64*w is consecutive.
        float lft = __shfl_up(cc.w, 1, 64);
        if (lane == 0) lft = sp[(size_t)y * NW + ((x0 - 1) & (NW - 1))];
        float rgt = __shfl_down(cc.x, 1, 64);
        if (lane == 63) rgt = sp[(size_t)y * NW + ((x0 + 4) & (NW - 1))];
        v4f un;
        un.x = cc.x + (D * (up.x + dn.x + lft + cc.y - 4.0f * cc.x) + rho * cc.x * (1.0f - cc.x));
        un.y = cc.y + (D * (up.y + dn.y + cc.x + cc.z - 4.0f * cc.y) + rho * cc.y * (1.0f - cc.y));
        un.z = cc.z + (D * (up.z + dn.z + cc.y + cc.w - 4.0f * cc.z) + rho * cc.z * (1.0f - cc.z));
        un.w = cc.w + (D * (up.w + dn.w + cc.z + rgt - 4.0f * cc.w) + rho * cc.w * (1.0f - cc.w));
        if (finalStep) __builtin_nontemporal_store(un, &((v4f*)(dp + (size_t)y * NW))[col4]);
        else ((v4f*)(dp + (size_t)y * NW))[col4] = un;
        acc += (un.x + un.y) + (un.z + un.w);
        up = cc; cc = dn;
    }

    // Next step's ch0 sum, only if step stepIdx+1 is active for this batch.
    if (stepIdx + 1 < tb) {
        float tot = blockReduce256(acc, sm);
        if (threadIdx.x == 0) atomicAdd((float*)&stepSums[(stepIdx + 1) * NB + b], tot);
    }
}

extern "C" void kernel_launch(void* const* d_in, const int* in_sizes, int n_in,
                              void* d_out, int out_size, void* d_ws, size_t ws_size,
                              hipStream_t stream) {
    const float* x = (const float*)d_in[0];
    const float* Wm = (const float*)d_in[1];
    const float* bv = (const float*)d_in[2];
    const int* t = (const int*)d_in[3];
    float* out = (float*)d_out;

    // ws layout: [u ping-pong: NB*PLANE floats][sumsAll: NB*NC][stepSums: NSTEPS*NB]
    float* wsU = (float*)d_ws;
    float* sumsAll = wsU + (size_t)NB * PLANE;
    float* stepSums = sumsAll + NB * NC;

    hipMemsetAsync(sumsAll, 0, sizeof(float) * (NB * NC + NSTEPS * NB), stream);

    mean_copy_kernel<<<NB * NC * 16, 256, 0, stream>>>(x, out, sumsAll, stepSums, t);

    // t in [0, NSTEPS) => step NSTEPS-1 is never active; launch only 7 steps.
    for (int i = 0; i < NSTEPS - 1; ++i) {
        dim3 grid(NSTRIP, NB);
        step_kernel<<<grid, 256, 0, stream>>>(x, out, wsU, sumsAll, stepSums,
                                              Wm, bv, t, i);
    }
}